// Round 4
// baseline (235.554 us; speedup 1.0000x reference)
//
#include <hip/hip_runtime.h>
#include <stdint.h>

// ---------------------------------------------------------------------------
// NonLocalBlock2D  B=16, C=512, I=256, N=3136. All-NT bf16 GEMMs, BK=64,
// both-sides LDS slot-swizzle (slot ^= row&7), counted vmcnt(8) dbuf.
// Chain:
//   xb  [b][3200][512] = x^T bf16 (rows>=3136 garbage, feeds discarded cols)
//   G1 (256^2, 8 waves): rows<512 -> P[b][512][3200] (g,ph; cols>=3136 zeroed)
//                        rows>=512 -> thT[b][3136][256] written transposed
//   G2 (128^2): Mf2 partials = ph .NT g, split-K 10x320
//   cvt: MT2[b][j][i] = (1/N) sum partials
//   GU (128^2): U = Ww .NT MT2    (U[c][j] = sum_i Ww[c,i] M[j,i])
//   G4 (128^2): out = U .NT thT + x + W_b
// Workspace:
//   xb  @ 0         : 52,428,800   (dead after G1; Mf2/MT2/U alias it)
//     Mf2 @ 0         : 41,943,040
//     MT2 @ 41943040  :  2,097,152
//     U   @ 44040192  :  4,194,304
//   thT @ 52428800  : 25,690,112
//   P   @ 78118912  : 52,428,800
//   W3  @ 130547712 :    786,432
//   Wwb @ 131334144 :    262,144
//   bias3 @ 131596288:      3,072   total ~131.6 MB
// ---------------------------------------------------------------------------

typedef unsigned short ushort_t;
typedef __attribute__((ext_vector_type(8))) short short8;
typedef __attribute__((ext_vector_type(4))) float f32x4;
typedef __attribute__((ext_vector_type(4))) unsigned short us4;
typedef __attribute__((ext_vector_type(8))) unsigned short us8;

#define NSP  3136
#define XNR  3200   // xb rows per batch
#define PLD  3200   // P row length

#define AS1(p) ((const __attribute__((address_space(1))) void*)(p))
#define AS3(p) ((__attribute__((address_space(3))) void*)(p))

__device__ inline ushort_t f2b(float f) {
  union { float f; uint32_t u; } c; c.f = f;
  uint32_t u = c.u;
  uint32_t r = (u + 0x7fffu + ((u >> 16) & 1u)) >> 16;
  return (ushort_t)r;
}

// MODE 1: P/thT = W3 .NT xb   (M=768, N=3328 tiles, K=512)  256^2 tile, 8 waves
// MODE 2: Mf2   = ph .NT g    (M=256, N=256, K=3200 split 10x320) f32, 128^2
// MODE 6: U     = Ww .NT MT2  (M=512, N=256, K=256) bf16, 128^2
// MODE 4: out   = U  .NT thT + x + W_b (M=512, N=3328 tiles, K=256) f32, 128^2
template<int MODE>
__global__ __launch_bounds__(MODE == 1 ? 512 : 256, 2) void gemm64(
    const ushort_t* __restrict__ Abase,
    const ushort_t* __restrict__ Bbase,
    void* __restrict__ Cbase, void* __restrict__ C2,
    const float* __restrict__ bias,
    const float* __restrict__ xres)
{
  constexpr int TB = (MODE == 1) ? 512 : 256;
  constexpr int MR = (MODE == 1) ? 8 : 4;       // m-frags per wave
  constexpr int WN = (MODE == 1) ? 4 : 2;       // waves along n
  constexpr int BM = 2 * MR * 16;               // 256 / 128
  constexpr int BN = WN * 64;                   // 256 / 128
  constexpr int CH = TB / 8;                    // rows per stage chunk

  // bijective XCD swizzle (all grids % 8 == 0)
  const int nwg = gridDim.x * gridDim.y * gridDim.z;
  int flat = blockIdx.x + gridDim.x * (blockIdx.y + gridDim.y * blockIdx.z);
  const int q = nwg >> 3;
  int swz = (flat & 7) * q + (flat >> 3);
  const int bx = swz % gridDim.x; int tmp = swz / gridDim.x;
  const int by = tmp % gridDim.y;
  const int bz = tmp / gridDim.y;

  int b, kc = 0, kbeg, kend, lda, ldb;
  const ushort_t *A, *B;
  if constexpr (MODE == 1) {
    b = bz; A = Abase; lda = 512;
    B = Bbase + (size_t)b * XNR * 512; ldb = 512;
    kbeg = 0; kend = 512;
  } else if constexpr (MODE == 2) {
    b = bz & 15; kc = bz >> 4;
    A = Abase + (size_t)b * 512 * PLD + (size_t)256 * PLD;  // ph rows
    B = Abase + (size_t)b * 512 * PLD;                      // g rows
    lda = PLD; ldb = PLD; kbeg = kc * 320; kend = kbeg + 320;
  } else if constexpr (MODE == 6) {
    b = bz; A = Abase; lda = 256;
    B = Bbase + (size_t)b * 65536; ldb = 256;
    kbeg = 0; kend = 256;
  } else {
    b = bz; A = Abase + (size_t)b * 131072; lda = 256;
    B = Bbase + (size_t)b * NSP * 256; ldb = 256;
    kbeg = 0; kend = 256;
  }

  const int m0 = bx * BM;
  const int n0 = by * BN;
  const int tid = threadIdx.x;
  const int lane = tid & 63;
  const int wid = tid >> 6;
  const int wm = wid / WN, wn = wid % WN;
  const int fr = lane & 15;
  const int fk = lane >> 4;       // 0..3

  __shared__ __align__(16) ushort_t As[2][BM * 64];
  __shared__ __align__(16) ushort_t Bs[2][BN * 64];

  f32x4 acc[MR][4];
#pragma unroll
  for (int i = 0; i < MR; ++i)
#pragma unroll
    for (int j = 0; j < 4; ++j) acc[i][j] = f32x4{0.f, 0.f, 0.f, 0.f};

  // stage: thread covers (row = j*CH + tid>>3, phys slot = tid&7); source col
  // pre-swizzled so that logical slot l = phys ^ (row&7) lands at phys.
  const int srow = tid >> 3;
  const int lsl = (tid & 7) ^ (srow & 7);
  const ushort_t* pa = A + (size_t)(m0 + srow) * lda + kbeg + lsl * 8;
  const ushort_t* pb = B + (size_t)(n0 + srow) * ldb + kbeg + lsl * 8;

#define STAGE(bufi) do {                                                              \
    __builtin_amdgcn_global_load_lds(AS1(pa),                    AS3(&As[bufi][tid * 8]), 16, 0, 0); \
    __builtin_amdgcn_global_load_lds(AS1(pa + (size_t)CH * lda), AS3(&As[bufi][TB * 8 + tid * 8]), 16, 0, 0); \
    __builtin_amdgcn_global_load_lds(AS1(pa + (size_t)2 * CH * lda), AS3(&As[bufi][2 * TB * 8 + tid * 8]), 16, 0, 0); \
    __builtin_amdgcn_global_load_lds(AS1(pa + (size_t)3 * CH * lda), AS3(&As[bufi][3 * TB * 8 + tid * 8]), 16, 0, 0); \
    __builtin_amdgcn_global_load_lds(AS1(pb),                    AS3(&Bs[bufi][tid * 8]), 16, 0, 0); \
    __builtin_amdgcn_global_load_lds(AS1(pb + (size_t)CH * ldb), AS3(&Bs[bufi][TB * 8 + tid * 8]), 16, 0, 0); \
    __builtin_amdgcn_global_load_lds(AS1(pb + (size_t)2 * CH * ldb), AS3(&Bs[bufi][2 * TB * 8 + tid * 8]), 16, 0, 0); \
    __builtin_amdgcn_global_load_lds(AS1(pb + (size_t)3 * CH * ldb), AS3(&Bs[bufi][3 * TB * 8 + tid * 8]), 16, 0, 0); \
    pa += 64; pb += 64;                                                               \
  } while (0)

  // read-side swizzled slot offsets (ushort units): slot = ((ks<<2)|fk) ^ (fr&7)
  const int sw = fr & 7;
  const int s0 = ((0 | fk) ^ sw) * 8;
  const int s1 = ((4 | fk) ^ sw) * 8;
  const int arow = (wm * MR * 16 + fr) * 64;
  const int brow = (wn * 64 + fr) * 64;

  asm volatile("s_waitcnt vmcnt(0)" ::: "memory");
  STAGE(0);

  const int nkt = (kend - kbeg) >> 6;
  for (int t = 0; t < nkt; ++t) {
    const int cur = t & 1;
    if (t + 1 < nkt) {
      STAGE(cur ^ 1);
      asm volatile("s_waitcnt vmcnt(8)" ::: "memory");  // cur's 8 landed
    } else {
      asm volatile("s_waitcnt vmcnt(0)" ::: "memory");
    }
    __builtin_amdgcn_s_barrier();
    __builtin_amdgcn_sched_barrier(0);

    short8 bf[4][2];
#pragma unroll
    for (int n = 0; n < 4; ++n) {
      bf[n][0] = *reinterpret_cast<const short8*>(&Bs[cur][brow + n * 1024 + s0]);
      bf[n][1] = *reinterpret_cast<const short8*>(&Bs[cur][brow + n * 1024 + s1]);
    }
#pragma unroll
    for (int pg = 0; pg < MR / 4; ++pg) {
      short8 af[4][2];
#pragma unroll
      for (int m = 0; m < 4; ++m) {
        af[m][0] = *reinterpret_cast<const short8*>(&As[cur][arow + (pg * 4 + m) * 1024 + s0]);
        af[m][1] = *reinterpret_cast<const short8*>(&As[cur][arow + (pg * 4 + m) * 1024 + s1]);
      }
      __builtin_amdgcn_s_setprio(1);
#pragma unroll
      for (int m = 0; m < 4; ++m)
#pragma unroll
        for (int n = 0; n < 4; ++n) {
          acc[pg * 4 + m][n] = __builtin_amdgcn_mfma_f32_16x16x32_bf16(af[m][0], bf[n][0], acc[pg * 4 + m][n], 0, 0, 0);
          acc[pg * 4 + m][n] = __builtin_amdgcn_mfma_f32_16x16x32_bf16(af[m][1], bf[n][1], acc[pg * 4 + m][n], 0, 0, 0);
        }
      __builtin_amdgcn_s_setprio(0);
    }
    __builtin_amdgcn_s_barrier();
  }
#undef STAGE

  // D layout: col = lane&15, row = fk*4 + reg
  if constexpr (MODE == 1) {
    if (m0 == 512) {   // th tile -> thT (transposed store, packed 8B)
      ushort_t* tT = (ushort_t*)C2;
#pragma unroll
      for (int m = 0; m < MR; ++m) {
        int jr = wm * 128 + m * 16 + fk * 4;     // 0..255
#pragma unroll
        for (int n = 0; n < 4; ++n) {
          int col = n0 + wn * 64 + n * 16 + fr;
          if (col < NSP) {
            us4 o;
#pragma unroll
            for (int r = 0; r < 4; ++r) o[r] = f2b(acc[m][n][r] + bias[512 + jr + r]);
            *reinterpret_cast<us4*>(&tT[((size_t)b * NSP + col) * 256 + jr]) = o;
          }
        }
      }
    } else {           // g/ph tiles -> P
      ushort_t* Pp = (ushort_t*)Cbase;
#pragma unroll
      for (int m = 0; m < MR; ++m) {
#pragma unroll
        for (int n = 0; n < 4; ++n) {
          int gcol = n0 + wn * 64 + n * 16 + fr;
          if (gcol < PLD) {
#pragma unroll
            for (int r = 0; r < 4; ++r) {
              int grow = m0 + wm * 128 + m * 16 + fk * 4 + r;
              ushort_t o = (gcol < NSP) ? f2b(acc[m][n][r] + bias[grow]) : (ushort_t)0;
              Pp[(size_t)b * 512 * PLD + (size_t)grow * PLD + gcol] = o;
            }
          }
        }
      }
    }
  } else if constexpr (MODE == 2) {
    float* Mf = (float*)Cbase;
#pragma unroll
    for (int m = 0; m < MR; ++m)
#pragma unroll
      for (int n = 0; n < 4; ++n) {
        int gcol = n0 + wn * 64 + n * 16 + fr;
#pragma unroll
        for (int r = 0; r < 4; ++r) {
          int grow = m0 + wm * 64 + m * 16 + fk * 4 + r;
          Mf[((size_t)kc * 16 + b) * 65536 + grow * 256 + gcol] = acc[m][n][r];
        }
      }
  } else if constexpr (MODE == 6) {
    ushort_t* U = (ushort_t*)Cbase;
#pragma unroll
    for (int m = 0; m < MR; ++m)
#pragma unroll
      for (int n = 0; n < 4; ++n) {
        int gcol = n0 + wn * 64 + n * 16 + fr;
#pragma unroll
        for (int r = 0; r < 4; ++r) {
          int grow = m0 + wm * 64 + m * 16 + fk * 4 + r;
          U[(size_t)b * 131072 + grow * 256 + gcol] = f2b(acc[m][n][r]);
        }
      }
  } else {
    float* out = (float*)Cbase;
#pragma unroll
    for (int m = 0; m < MR; ++m)
#pragma unroll
      for (int n = 0; n < 4; ++n) {
        int gcol = n0 + wn * 64 + n * 16 + fr;
        if (gcol < NSP) {
#pragma unroll
          for (int r = 0; r < 4; ++r) {
            int grow = m0 + wm * 64 + m * 16 + fk * 4 + r;
            size_t o = ((size_t)b * 512 + grow) * NSP + gcol;
            out[o] = acc[m][n][r] + bias[grow] + xres[o];
          }
        }
      }
  }
}

// x [b][512][3136] f32 -> xb [b][3200][512] bf16 (rows >=3136 left garbage)
__global__ __launch_bounds__(256) void transp_x(const float* __restrict__ x,
                                                ushort_t* __restrict__ xb)
{
  const int nt = blockIdx.x, ct = blockIdx.y, b = blockIdx.z;
  const int t = threadIdx.x;
  const int n0 = nt * 64, c0 = ct * 64;
  __shared__ float Ls[64 * 65];

  const float* xs = x + (size_t)b * 512 * NSP;
#pragma unroll
  for (int p = 0; p < 4; ++p) {
    int cl = p * 16 + (t >> 4);
    int nl = (t & 15) * 4;
    f32x4 v = *reinterpret_cast<const f32x4*>(&xs[(size_t)(c0 + cl) * NSP + n0 + nl]);
    Ls[cl * 65 + nl + 0] = v[0];
    Ls[cl * 65 + nl + 1] = v[1];
    Ls[cl * 65 + nl + 2] = v[2];
    Ls[cl * 65 + nl + 3] = v[3];
  }
  __syncthreads();
#pragma unroll
  for (int it = 0; it < 2; ++it) {
    int idx = it * 256 + t; int nl = idx >> 3, cc = idx & 7;
    us8 o;
#pragma unroll
    for (int j = 0; j < 8; ++j) o[j] = f2b(Ls[(cc * 8 + j) * 65 + nl]);
    *reinterpret_cast<us8*>(&xb[((size_t)b * XNR + n0 + nl) * 512 + c0 + cc * 8]) = o;
  }
}

__global__ __launch_bounds__(256) void prep_weights(
    const float* __restrict__ g_w, const float* __restrict__ ph_w,
    const float* __restrict__ th_w, const float* __restrict__ W_w,
    const float* __restrict__ g_b, const float* __restrict__ ph_b,
    const float* __restrict__ th_b,
    ushort_t* __restrict__ W3, ushort_t* __restrict__ Wwb,
    float* __restrict__ bias3)
{
  int i = blockIdx.x * 256 + threadIdx.x;
  if (i < 393216) {
    int row = i >> 9, col = i & 511;
    float v = (row < 256) ? g_w[row * 512 + col]
            : (row < 512) ? ph_w[(row - 256) * 512 + col]
                          : th_w[(row - 512) * 512 + col];
    W3[i] = f2b(v);
  } else if (i < 524288) {
    Wwb[i - 393216] = f2b(W_w[i - 393216]);
  } else if (i < 525056) {
    int r = i - 524288;
    bias3[r] = (r < 256) ? g_b[r] : (r < 512) ? ph_b[r - 256] : th_b[r - 512];
  }
}

__global__ __launch_bounds__(256) void cvt_M(const float* __restrict__ Mf,
                                             ushort_t* __restrict__ MT)
{
  int i = blockIdx.x * 256 + threadIdx.x;   // 16*256*256 = 1048576
  const int SL = 1048576;
  float s = 0.f;
#pragma unroll
  for (int k = 0; k < 10; ++k) s += Mf[(size_t)k * SL + i];
  MT[i] = f2b(s * (1.0f / 3136.0f));
}

extern "C" void kernel_launch(void* const* d_in, const int* in_sizes, int n_in,
                              void* d_out, int out_size, void* d_ws, size_t ws_size,
                              hipStream_t stream) {
  const float* x    = (const float*)d_in[0];
  const float* g_w  = (const float*)d_in[1];
  const float* g_b  = (const float*)d_in[2];
  const float* th_w = (const float*)d_in[3];
  const float* th_b = (const float*)d_in[4];
  const float* ph_w = (const float*)d_in[5];
  const float* ph_b = (const float*)d_in[6];
  const float* W_w  = (const float*)d_in[7];
  const float* W_b  = (const float*)d_in[8];

  char* ws = (char*)d_ws;
  ushort_t* xb   = (ushort_t*)(ws + 0);
  float*    Mf2  = (float*)(ws + 0);              // aliases xb (dead after G1)
  ushort_t* MT2  = (ushort_t*)(ws + 41943040);
  ushort_t* U    = (ushort_t*)(ws + 44040192);
  ushort_t* thT  = (ushort_t*)(ws + 52428800);
  ushort_t* P    = (ushort_t*)(ws + 78118912);
  ushort_t* W3   = (ushort_t*)(ws + 130547712);
  ushort_t* Wwb  = (ushort_t*)(ws + 131334144);
  float*    bias3 = (float*)(ws + 131596288);

  prep_weights<<<2052, 256, 0, stream>>>(g_w, ph_w, th_w, W_w, g_b, ph_b, th_b,
                                         W3, Wwb, bias3);
  transp_x<<<dim3(49, 8, 16), 256, 0, stream>>>(x, xb);

  // G1: P(g,ph) + thT = W3 .NT xb (+bias3)   M=768, N=3328-tiled, K=512
  gemm64<1><<<dim3(3, 13, 16), 512, 0, stream>>>(W3, xb, P, thT, bias3, nullptr);
  // G2: Mf2 partials = ph .NT g   split-K 10x320
  gemm64<2><<<dim3(2, 2, 160), 256, 0, stream>>>(P, nullptr, Mf2, nullptr, nullptr, nullptr);
  cvt_M<<<4096, 256, 0, stream>>>(Mf2, MT2);
  // GU: U = Wwb .NT MT2            M=512, N=256, K=256
  gemm64<6><<<dim3(4, 2, 16), 256, 0, stream>>>(Wwb, MT2, U, nullptr, nullptr, nullptr);
  // G4: out = U .NT thT + x + W_b  M=512, N=3328-tiled, K=256
  gemm64<4><<<dim3(4, 26, 16), 256, 0, stream>>>(U, thT, d_out, nullptr, W_b, x);
}

// Round 5
// 234.571 us; speedup vs baseline: 1.0042x; 1.0042x over previous
//
#include <hip/hip_runtime.h>
#include <stdint.h>

// ---------------------------------------------------------------------------
// NonLocalBlock2D  B=16, C=512, I=256, N=3136.
//   xb  [b][3200][512] = x^T bf16
//   G1 (256^2, 8-phase schedule): rows<512 -> P[b][512][3200] (g,ph)
//                                 rows>=512 -> thT[b][3136][256] (transposed store)
//   G2 (128^2): Mf2 partials = ph .NT g, split-K 10x320
//   cvt: MT2 = (1/N) sum partials
//   GU (128^2): U = Ww .NT MT2
//   G4 (128^2): out = U .NT thT + x + W_b
// G1 uses the m201-style 8-phase 256^2 template: BK=64, 8 waves (2Mx4N),
// LDS 128 KiB (2dbuf x 2half x 128 x 64 x {A,B}), both-sides XOR swizzle,
// counted vmcnt(6) once per K-tile, setprio around each 16-MFMA cluster.
// ---------------------------------------------------------------------------

typedef unsigned short ushort_t;
typedef __attribute__((ext_vector_type(8))) short short8;
typedef __attribute__((ext_vector_type(4))) float f32x4;
typedef __attribute__((ext_vector_type(4))) unsigned short us4;
typedef __attribute__((ext_vector_type(8))) unsigned short us8;

#define NSP  3136
#define XNR  3200
#define PLD  3200

#define AS1(p) ((const __attribute__((address_space(1))) void*)(p))
#define AS3(p) ((__attribute__((address_space(3))) void*)(p))

__device__ inline ushort_t f2b(float f) {
  union { float f; uint32_t u; } c; c.f = f;
  uint32_t u = c.u;
  uint32_t r = (u + 0x7fffu + ((u >> 16) & 1u)) >> 16;
  return (ushort_t)r;
}

// ============================ G1: 8-phase 256^2 ============================
__global__ __launch_bounds__(512, 2) void g1_8phase(
    const ushort_t* __restrict__ W3,
    const ushort_t* __restrict__ xbase,
    ushort_t* __restrict__ P,
    ushort_t* __restrict__ thT,
    const float* __restrict__ bias)
{
  const int nwg = gridDim.x * gridDim.y * gridDim.z;   // 624, %8==0
  int flat = blockIdx.x + gridDim.x * (blockIdx.y + gridDim.y * blockIdx.z);
  const int q = nwg >> 3;
  int swz = (flat & 7) * q + (flat >> 3);
  const int bx = swz % gridDim.x; int tmp = swz / gridDim.x;
  const int by = tmp % gridDim.y;
  const int b  = tmp / gridDim.y;

  const int m0 = bx * 256;
  const int n0 = by * 256;
  const ushort_t* Ag = W3;
  const ushort_t* Bg = xbase + (size_t)b * XNR * 512;

  const int tid = threadIdx.x;
  const int lane = tid & 63;
  const int wid = tid >> 6;
  const int wm = wid >> 2;            // 0..1  (m-half)
  const int wn = wid & 3;             // 0..3
  const int fr = lane & 15;
  const int fk = lane >> 4;           // 0..3
  const int hB = wn >> 1;             // B half
  const int rB0 = (wn & 1) * 64;
  const int s0 = ((fk) ^ (fr & 7)) * 8;        // k-half0 swizzled slot
  const int s1 = ((4 | fk) ^ (fr & 7)) * 8;    // k-half1
  const int rth = tid >> 3;                    // 0..63
  const int swc = ((tid & 7) ^ ((tid >> 3) & 7)) * 8;  // pre-swizzled src col

  __shared__ __align__(16) ushort_t As[2][2][8192];  // [dbuf][half][128*64]
  __shared__ __align__(16) ushort_t Bs[2][2][8192];

  f32x4 acc[8][4];
#pragma unroll
  for (int i = 0; i < 8; ++i)
#pragma unroll
    for (int j = 0; j < 4; ++j) acc[i][j] = f32x4{0.f, 0.f, 0.f, 0.f};

#define STG_A(h, kt, BUF) do { \
    const ushort_t* s_ = Ag + (size_t)(m0 + (h) * 128 + rth) * 512 + (kt) * 64 + swc; \
    __builtin_amdgcn_global_load_lds(AS1(s_), AS3(&As[BUF][h][tid * 8]), 16, 0, 0); \
    __builtin_amdgcn_global_load_lds(AS1(s_ + 64 * 512), AS3(&As[BUF][h][4096 + tid * 8]), 16, 0, 0); \
  } while (0)
#define STG_B(h, kt, BUF) do { \
    const ushort_t* s_ = Bg + (size_t)(n0 + (h) * 128 + rth) * 512 + (kt) * 64 + swc; \
    __builtin_amdgcn_global_load_lds(AS1(s_), AS3(&Bs[BUF][h][tid * 8]), 16, 0, 0); \
    __builtin_amdgcn_global_load_lds(AS1(s_ + 64 * 512), AS3(&Bs[BUF][h][4096 + tid * 8]), 16, 0, 0); \
  } while (0)

#define BARR __builtin_amdgcn_s_barrier()
#define LGKM0 do { asm volatile("s_waitcnt lgkmcnt(0)" ::: "memory"); \
                   __builtin_amdgcn_sched_barrier(0); } while (0)
#define MF16(AF, BF, OFS) do { \
    __builtin_amdgcn_s_setprio(1); \
    _Pragma("unroll") for (int mf_ = 0; mf_ < 4; ++mf_) \
    _Pragma("unroll") for (int nf_ = 0; nf_ < 4; ++nf_) \
      acc[(OFS) + mf_][nf_] = __builtin_amdgcn_mfma_f32_16x16x32_bf16( \
          AF[mf_], BF[nf_], acc[(OFS) + mf_][nf_], 0, 0, 0); \
    __builtin_amdgcn_s_setprio(0); \
  } while (0)

  // TILE T (4 phases).  Region safety: A0/A1(T) last read ph3; B0/B1(T) last
  // read ph2.  Issues: ph1: B1(T+1) [other buf]; ph3: B0(T+2) [B0(T) done ph2];
  // ph4: A0,A1(T+2) [done ph3]; vmcnt(6) at ph4 => T+1 fully landed.
#define TILE(T, CUR, DO_B1, DO_T2, VMN) do { \
    short8 a0[4], a1[4], a2[4], a3[4], b0[4], b1[4]; \
    _Pragma("unroll") for (int i = 0; i < 4; ++i) \
      a0[i] = *(const short8*)&As[CUR][wm][(i * 16 + fr) * 64 + s0]; \
    _Pragma("unroll") for (int i = 0; i < 4; ++i) \
      b0[i] = *(const short8*)&Bs[CUR][hB][(rB0 + i * 16 + fr) * 64 + s0]; \
    if (DO_B1) STG_B(1, (T) + 1, (CUR) ^ 1); \
    BARR; LGKM0; MF16(a0, b0, 0); BARR; \
    _Pragma("unroll") for (int i = 0; i < 4; ++i) \
      a1[i] = *(const short8*)&As[CUR][wm][((i + 4) * 16 + fr) * 64 + s0]; \
    _Pragma("unroll") for (int i = 0; i < 4; ++i) \
      b1[i] = *(const short8*)&Bs[CUR][hB][(rB0 + i * 16 + fr) * 64 + s1]; \
    BARR; LGKM0; MF16(a1, b0, 4); BARR; \
    _Pragma("unroll") for (int i = 0; i < 4; ++i) \
      a2[i] = *(const short8*)&As[CUR][wm][(i * 16 + fr) * 64 + s1]; \
    _Pragma("unroll") for (int i = 0; i < 4; ++i) \
      a3[i] = *(const short8*)&As[CUR][wm][((i + 4) * 16 + fr) * 64 + s1]; \
    if (DO_T2) STG_B(0, (T) + 2, (CUR)); \
    BARR; LGKM0; MF16(a2, b1, 0); BARR; \
    if (DO_T2) { STG_A(0, (T) + 2, (CUR)); STG_A(1, (T) + 2, (CUR)); } \
    if ((VMN) == 6) asm volatile("s_waitcnt vmcnt(6)" ::: "memory"); \
    else if ((VMN) == 0) asm volatile("s_waitcnt vmcnt(0)" ::: "memory"); \
    BARR; MF16(a3, b1, 4); BARR; \
  } while (0)

  // prologue: tile0 full (8 loads) + tile1 {B0,A0,A1} (6 loads)
  asm volatile("s_waitcnt vmcnt(0)" ::: "memory");
  STG_A(0, 0, 0); STG_A(1, 0, 0); STG_B(0, 0, 0); STG_B(1, 0, 0);
  STG_B(0, 1, 1); STG_A(0, 1, 1); STG_A(1, 1, 1);
  asm volatile("s_waitcnt vmcnt(6)" ::: "memory");
  BARR;

  for (int t = 0; t < 6; t += 2) { TILE(t, 0, 1, 1, 6); TILE(t + 1, 1, 1, 1, 6); }
  TILE(6, 0, 1, 0, 0);
  TILE(7, 1, 0, 0, -1);

#undef TILE
#undef STG_A
#undef STG_B

  // epilogue.  D: col = lane&15, row = fk*4 + r
  if (m0 == 512) {     // th rows -> thT transposed (packed 8B)
#pragma unroll
    for (int m = 0; m < 8; ++m) {
      int jr = wm * 128 + m * 16 + fk * 4;
#pragma unroll
      for (int n = 0; n < 4; ++n) {
        int col = n0 + wn * 64 + n * 16 + fr;
        if (col < NSP) {
          us4 o;
#pragma unroll
          for (int r = 0; r < 4; ++r) o[r] = f2b(acc[m][n][r] + bias[512 + jr + r]);
          *reinterpret_cast<us4*>(&thT[((size_t)b * NSP + col) * 256 + jr]) = o;
        }
      }
    }
  } else {             // g/ph rows -> P
#pragma unroll
    for (int m = 0; m < 8; ++m) {
#pragma unroll
      for (int n = 0; n < 4; ++n) {
        int gcol = n0 + wn * 64 + n * 16 + fr;
        if (gcol < PLD) {
#pragma unroll
          for (int r = 0; r < 4; ++r) {
            int grow = m0 + wm * 128 + m * 16 + fk * 4 + r;
            ushort_t o = (gcol < NSP) ? f2b(acc[m][n][r] + bias[grow]) : (ushort_t)0;
            P[(size_t)b * 512 * PLD + (size_t)grow * PLD + gcol] = o;
          }
        }
      }
    }
  }
}

// ==================== small GEMMs (R4 structure, 128^2) ====================
// MODE 2: Mf2 = ph .NT g    (M=256, N=256, K=3200 split 10x320) f32
// MODE 6: U   = Ww .NT MT2  (M=512, N=256, K=256) bf16
// MODE 4: out = U  .NT thT + x + W_b (M=512, N=3328 tiles, K=256) f32
template<int MODE>
__global__ __launch_bounds__(256, 2) void gemm64(
    const ushort_t* __restrict__ Abase,
    const ushort_t* __restrict__ Bbase,
    void* __restrict__ Cbase,
    const float* __restrict__ bias,
    const float* __restrict__ xres)
{
  constexpr int TB = 256;
  constexpr int MR = 4;
  constexpr int WN = 2;
  constexpr int CH = TB / 8;

  const int nwg = gridDim.x * gridDim.y * gridDim.z;
  int flat = blockIdx.x + gridDim.x * (blockIdx.y + gridDim.y * blockIdx.z);
  const int q = nwg >> 3;
  int swz = (flat & 7) * q + (flat >> 3);
  const int bx = swz % gridDim.x; int tmp = swz / gridDim.x;
  const int by = tmp % gridDim.y;
  const int bz = tmp / gridDim.y;

  int b, kc = 0, kbeg, kend, lda, ldb;
  const ushort_t *A, *B;
  if constexpr (MODE == 2) {
    b = bz & 15; kc = bz >> 4;
    A = Abase + (size_t)b * 512 * PLD + (size_t)256 * PLD;  // ph
    B = Abase + (size_t)b * 512 * PLD;                      // g
    lda = PLD; ldb = PLD; kbeg = kc * 320; kend = kbeg + 320;
  } else if constexpr (MODE == 6) {
    b = bz; A = Abase; lda = 256;
    B = Bbase + (size_t)b * 65536; ldb = 256;
    kbeg = 0; kend = 256;
  } else {
    b = bz; A = Abase + (size_t)b * 131072; lda = 256;
    B = Bbase + (size_t)b * NSP * 256; ldb = 256;
    kbeg = 0; kend = 256;
  }

  const int m0 = bx * 128;
  const int n0 = by * 128;
  const int tid = threadIdx.x;
  const int lane = tid & 63;
  const int wid = tid >> 6;
  const int wm = wid / WN, wn = wid % WN;
  const int fr = lane & 15;
  const int fk = lane >> 4;

  __shared__ __align__(16) ushort_t As[2][128 * 64];
  __shared__ __align__(16) ushort_t Bs[2][128 * 64];

  f32x4 acc[MR][4];
#pragma unroll
  for (int i = 0; i < MR; ++i)
#pragma unroll
    for (int j = 0; j < 4; ++j) acc[i][j] = f32x4{0.f, 0.f, 0.f, 0.f};

  const int srow = tid >> 3;
  const int lsl = (tid & 7) ^ (srow & 7);
  const ushort_t* pa = A + (size_t)(m0 + srow) * lda + kbeg + lsl * 8;
  const ushort_t* pb = B + (size_t)(n0 + srow) * ldb + kbeg + lsl * 8;

#define STAGE(bufi) do {                                                              \
    __builtin_amdgcn_global_load_lds(AS1(pa),                    AS3(&As[bufi][tid * 8]), 16, 0, 0); \
    __builtin_amdgcn_global_load_lds(AS1(pa + (size_t)CH * lda), AS3(&As[bufi][TB * 8 + tid * 8]), 16, 0, 0); \
    __builtin_amdgcn_global_load_lds(AS1(pa + (size_t)2 * CH * lda), AS3(&As[bufi][2 * TB * 8 + tid * 8]), 16, 0, 0); \
    __builtin_amdgcn_global_load_lds(AS1(pa + (size_t)3 * CH * lda), AS3(&As[bufi][3 * TB * 8 + tid * 8]), 16, 0, 0); \
    __builtin_amdgcn_global_load_lds(AS1(pb),                    AS3(&Bs[bufi][tid * 8]), 16, 0, 0); \
    __builtin_amdgcn_global_load_lds(AS1(pb + (size_t)CH * ldb), AS3(&Bs[bufi][TB * 8 + tid * 8]), 16, 0, 0); \
    __builtin_amdgcn_global_load_lds(AS1(pb + (size_t)2 * CH * ldb), AS3(&Bs[bufi][2 * TB * 8 + tid * 8]), 16, 0, 0); \
    __builtin_amdgcn_global_load_lds(AS1(pb + (size_t)3 * CH * ldb), AS3(&Bs[bufi][3 * TB * 8 + tid * 8]), 16, 0, 0); \
    pa += 64; pb += 64;                                                               \
  } while (0)

  const int sw = fr & 7;
  const int s0 = ((0 | fk) ^ sw) * 8;
  const int s1 = ((4 | fk) ^ sw) * 8;
  const int arow = (wm * MR * 16 + fr) * 64;
  const int brow = (wn * 64 + fr) * 64;

  asm volatile("s_waitcnt vmcnt(0)" ::: "memory");
  STAGE(0);

  const int nkt = (kend - kbeg) >> 6;
  for (int t = 0; t < nkt; ++t) {
    const int cur = t & 1;
    if (t + 1 < nkt) {
      STAGE(cur ^ 1);
      asm volatile("s_waitcnt vmcnt(8)" ::: "memory");
    } else {
      asm volatile("s_waitcnt vmcnt(0)" ::: "memory");
    }
    __builtin_amdgcn_s_barrier();
    __builtin_amdgcn_sched_barrier(0);

    short8 bf[4][2];
#pragma unroll
    for (int n = 0; n < 4; ++n) {
      bf[n][0] = *reinterpret_cast<const short8*>(&Bs[cur][brow + n * 1024 + s0]);
      bf[n][1] = *reinterpret_cast<const short8*>(&Bs[cur][brow + n * 1024 + s1]);
    }
    short8 af[4][2];
#pragma unroll
    for (int m = 0; m < 4; ++m) {
      af[m][0] = *reinterpret_cast<const short8*>(&As[cur][arow + m * 1024 + s0]);
      af[m][1] = *reinterpret_cast<const short8*>(&As[cur][arow + m * 1024 + s1]);
    }
    __builtin_amdgcn_s_setprio(1);
#pragma unroll
    for (int m = 0; m < 4; ++m)
#pragma unroll
      for (int n = 0; n < 4; ++n) {
        acc[m][n] = __builtin_amdgcn_mfma_f32_16x16x32_bf16(af[m][0], bf[n][0], acc[m][n], 0, 0, 0);
        acc[m][n] = __builtin_amdgcn_mfma_f32_16x16x32_bf16(af[m][1], bf[n][1], acc[m][n], 0, 0, 0);
      }
    __builtin_amdgcn_s_setprio(0);
    __builtin_amdgcn_s_barrier();
  }
#undef STAGE

  if constexpr (MODE == 2) {
    float* Mf = (float*)Cbase;
#pragma unroll
    for (int m = 0; m < MR; ++m)
#pragma unroll
      for (int n = 0; n < 4; ++n) {
        int gcol = n0 + wn * 64 + n * 16 + fr;
#pragma unroll
        for (int r = 0; r < 4; ++r) {
          int grow = m0 + wm * 64 + m * 16 + fk * 4 + r;
          Mf[((size_t)kc * 16 + b) * 65536 + grow * 256 + gcol] = acc[m][n][r];
        }
      }
  } else if constexpr (MODE == 6) {
    ushort_t* U = (ushort_t*)Cbase;
#pragma unroll
    for (int m = 0; m < MR; ++m)
#pragma unroll
      for (int n = 0; n < 4; ++n) {
        int gcol = n0 + wn * 64 + n * 16 + fr;
#pragma unroll
        for (int r = 0; r < 4; ++r) {
          int grow = m0 + wm * 64 + m * 16 + fk * 4 + r;
          U[(size_t)b * 131072 + grow * 256 + gcol] = f2b(acc[m][n][r]);
        }
      }
  } else {
    float* out = (float*)Cbase;
#pragma unroll
    for (int m = 0; m < MR; ++m)
#pragma unroll
      for (int n = 0; n < 4; ++n) {
        int gcol = n0 + wn * 64 + n * 16 + fr;
        if (gcol < NSP) {
#pragma unroll
          for (int r = 0; r < 4; ++r) {
            int grow = m0 + wm * 64 + m * 16 + fk * 4 + r;
            size_t o = ((size_t)b * 512 + grow) * NSP + gcol;
            out[o] = acc[m][n][r] + bias[grow] + xres[o];
          }
        }
      }
  }
}

// x [b][512][3136] f32 -> xb [b][3200][512] bf16
__global__ __launch_bounds__(256) void transp_x(const float* __restrict__ x,
                                                ushort_t* __restrict__ xb)
{
  const int nt = blockIdx.x, ct = blockIdx.y, b = blockIdx.z;
  const int t = threadIdx.x;
  const int n0 = nt * 64, c0 = ct * 64;
  __shared__ float Ls[64 * 65];

  const float* xs = x + (size_t)b * 512 * NSP;
#pragma unroll
  for (int p = 0; p < 4; ++p) {
    int cl = p * 16 + (t >> 4);
    int nl = (t & 15) * 4;
    f32x4 v = *reinterpret_cast<const f32x4*>(&xs[(size_t)(c0 + cl) * NSP + n0 + nl]);
    Ls[cl * 65 + nl + 0] = v[0];
    Ls[cl * 65 + nl + 1] = v[1];
    Ls[cl * 65 + nl + 2] = v[2];
    Ls[cl * 65 + nl + 3] = v[3];
  }
  __syncthreads();
#pragma unroll
  for (int it = 0; it < 2; ++it) {
    int idx = it * 256 + t; int nl = idx >> 3, cc = idx & 7;
    us8 o;
#pragma unroll
    for (int j = 0; j < 8; ++j) o[j] = f2b(Ls[(cc * 8 + j) * 65 + nl]);
    *reinterpret_cast<us8*>(&xb[((size_t)b * XNR + n0 + nl) * 512 + c0 + cc * 8]) = o;
  }
}

__global__ __launch_bounds__(256) void prep_weights(
    const float* __restrict__ g_w, const float* __restrict__ ph_w,
    const float* __restrict__ th_w, const float* __restrict__ W_w,
    const float* __restrict__ g_b, const float* __restrict__ ph_b,
    const float* __restrict__ th_b,
    ushort_t* __restrict__ W3, ushort_t* __restrict__ Wwb,
    float* __restrict__ bias3)
{
  int i = blockIdx.x * 256 + threadIdx.x;
  if (i < 393216) {
    int row = i >> 9, col = i & 511;
    float v = (row < 256) ? g_w[row * 512 + col]
            : (row < 512) ? ph_w[(row - 256) * 512 + col]
                          : th_w[(row - 512) * 512 + col];
    W3[i] = f2b(v);
  } else if (i < 524288) {
    Wwb[i - 393216] = f2b(W_w[i - 393216]);
  } else if (i < 525056) {
    int r = i - 524288;
    bias3[r] = (r < 256) ? g_b[r] : (r < 512) ? ph_b[r - 256] : th_b[r - 512];
  }
}

__global__ __launch_bounds__(256) void cvt_M(const float* __restrict__ Mf,
                                             ushort_t* __restrict__ MT)
{
  int i = blockIdx.x * 256 + threadIdx.x;   // 16*256*256
  const int SL = 1048576;
  float s = 0.f;
#pragma unroll
  for (int k = 0; k < 10; ++k) s += Mf[(size_t)k * SL + i];
  MT[i] = f2b(s * (1.0f / 3136.0f));
}

extern "C" void kernel_launch(void* const* d_in, const int* in_sizes, int n_in,
                              void* d_out, int out_size, void* d_ws, size_t ws_size,
                              hipStream_t stream) {
  const float* x    = (const float*)d_in[0];
  const float* g_w  = (const float*)d_in[1];
  const float* g_b  = (const float*)d_in[2];
  const float* th_w = (const float*)d_in[3];
  const float* th_b = (const float*)d_in[4];
  const float* ph_w = (const float*)d_in[5];
  const float* ph_b = (const float*)d_in[6];
  const float* W_w  = (const float*)d_in[7];
  const float* W_b  = (const float*)d_in[8];

  char* ws = (char*)d_ws;
  ushort_t* xb   = (ushort_t*)(ws + 0);
  float*    Mf2  = (float*)(ws + 0);              // aliases xb (dead after G1)
  ushort_t* MT2  = (ushort_t*)(ws + 41943040);
  ushort_t* U    = (ushort_t*)(ws + 44040192);
  ushort_t* thT  = (ushort_t*)(ws + 52428800);
  ushort_t* P    = (ushort_t*)(ws + 78118912);
  ushort_t* W3   = (ushort_t*)(ws + 130547712);
  ushort_t* Wwb  = (ushort_t*)(ws + 131334144);
  float*    bias3 = (float*)(ws + 131596288);

  prep_weights<<<2052, 256, 0, stream>>>(g_w, ph_w, th_w, W_w, g_b, ph_b, th_b,
                                         W3, Wwb, bias3);
  transp_x<<<dim3(49, 8, 16), 256, 0, stream>>>(x, xb);

  // G1: P(g,ph) + thT = W3 .NT xb (+bias3)   M=768, N=3328-tiled, K=512
  g1_8phase<<<dim3(3, 13, 16), 512, 0, stream>>>(W3, xb, P, thT, bias3);
  // G2: Mf2 partials = ph .NT g   split-K 10x320
  gemm64<2><<<dim3(2, 2, 160), 256, 0, stream>>>(P, nullptr, Mf2, nullptr, nullptr);
  cvt_M<<<4096, 256, 0, stream>>>(Mf2, MT2);
  // GU: U = Wwb .NT MT2            M=512, N=256, K=256
  gemm64<6><<<dim3(4, 2, 16), 256, 0, stream>>>(Wwb, MT2, U, nullptr, nullptr);
  // G4: out = U .NT thT + x + W_b  M=512, N=3328-tiled, K=256
  gemm64<4><<<dim3(4, 26, 16), 256, 0, stream>>>(U, thT, d_out, W_b, x);
}

// Round 6
// 188.192 us; speedup vs baseline: 1.2517x; 1.2464x over previous
//
#include <hip/hip_runtime.h>
#include <stdint.h>

// ---------------------------------------------------------------------------
// NonLocalBlock2D  B=16, C=512, I=256, N=3136.
//   xb  [b][3200][512] = x^T bf16
//   G1 (256^2, 8-phase): rows<512 -> P[b][512][3200] (g,ph)
//                        rows>=512 -> thT[b][3136][256] (transposed store)
//   Epilogues go through a 128KiB LDS staging tile -> coalesced us8 stores.
//   G2 (128^2): Mf2 partials = ph .NT g, split-K 5x640
//   cvt: MT2 = (1/N) sum partials
//   GU (128^2): U = Ww .NT MT2
//   G4 (128^2): out = U .NT thT + x + W_b
// ---------------------------------------------------------------------------

typedef unsigned short ushort_t;
typedef __attribute__((ext_vector_type(8))) short short8;
typedef __attribute__((ext_vector_type(4))) float f32x4;
typedef __attribute__((ext_vector_type(4))) unsigned short us4;
typedef __attribute__((ext_vector_type(8))) unsigned short us8;

#define NSP  3136
#define XNR  3200
#define PLD  3200

#define AS1(p) ((const __attribute__((address_space(1))) void*)(p))
#define AS3(p) ((__attribute__((address_space(3))) void*)(p))

__device__ inline ushort_t f2b(float f) {
  union { float f; uint32_t u; } c; c.f = f;
  uint32_t u = c.u;
  uint32_t r = (u + 0x7fffu + ((u >> 16) & 1u)) >> 16;
  return (ushort_t)r;
}

// ============================ G1: 8-phase 256^2 ============================
__global__ __launch_bounds__(512, 2) void g1_8phase(
    const ushort_t* __restrict__ W3,
    const ushort_t* __restrict__ xbase,
    ushort_t* __restrict__ P,
    ushort_t* __restrict__ thT,
    const float* __restrict__ bias)
{
  const int nwg = gridDim.x * gridDim.y * gridDim.z;   // 624, %8==0
  int flat = blockIdx.x + gridDim.x * (blockIdx.y + gridDim.y * blockIdx.z);
  const int q = nwg >> 3;
  int swz = (flat & 7) * q + (flat >> 3);
  const int bx = swz % gridDim.x; int tmp = swz / gridDim.x;
  const int by = tmp % gridDim.y;
  const int b  = tmp / gridDim.y;

  const int m0 = bx * 256;
  const int n0 = by * 256;
  const ushort_t* Ag = W3;
  const ushort_t* Bg = xbase + (size_t)b * XNR * 512;

  const int tid = threadIdx.x;
  const int lane = tid & 63;
  const int wid = tid >> 6;
  const int wm = wid >> 2;            // 0..1  (m-half)
  const int wn = wid & 3;             // 0..3
  const int fr = lane & 15;
  const int fk = lane >> 4;           // 0..3
  const int hB = wn >> 1;             // B half
  const int rB0 = (wn & 1) * 64;
  const int s0 = ((fk) ^ (fr & 7)) * 8;        // k-half0 swizzled slot
  const int s1 = ((4 | fk) ^ (fr & 7)) * 8;    // k-half1
  const int rth = tid >> 3;                    // 0..63
  const int swc = ((tid & 7) ^ ((tid >> 3) & 7)) * 8;  // pre-swizzled src col

  __shared__ __align__(16) ushort_t SM[65536];          // 128 KiB, re-used by epilogue
  ushort_t (*As)[2][8192] = (ushort_t(*)[2][8192])(SM);
  ushort_t (*Bs)[2][8192] = (ushort_t(*)[2][8192])(SM + 32768);

  f32x4 acc[8][4];
#pragma unroll
  for (int i = 0; i < 8; ++i)
#pragma unroll
    for (int j = 0; j < 4; ++j) acc[i][j] = f32x4{0.f, 0.f, 0.f, 0.f};

#define STG_A(h, kt, BUF) do { \
    const ushort_t* s_ = Ag + (size_t)(m0 + (h) * 128 + rth) * 512 + (kt) * 64 + swc; \
    __builtin_amdgcn_global_load_lds(AS1(s_), AS3(&As[BUF][h][tid * 8]), 16, 0, 0); \
    __builtin_amdgcn_global_load_lds(AS1(s_ + 64 * 512), AS3(&As[BUF][h][4096 + tid * 8]), 16, 0, 0); \
  } while (0)
#define STG_B(h, kt, BUF) do { \
    const ushort_t* s_ = Bg + (size_t)(n0 + (h) * 128 + rth) * 512 + (kt) * 64 + swc; \
    __builtin_amdgcn_global_load_lds(AS1(s_), AS3(&Bs[BUF][h][tid * 8]), 16, 0, 0); \
    __builtin_amdgcn_global_load_lds(AS1(s_ + 64 * 512), AS3(&Bs[BUF][h][4096 + tid * 8]), 16, 0, 0); \
  } while (0)

#define BARR __builtin_amdgcn_s_barrier()
#define LGKM0 do { asm volatile("s_waitcnt lgkmcnt(0)" ::: "memory"); \
                   __builtin_amdgcn_sched_barrier(0); } while (0)
#define MF16(AF, BF, OFS) do { \
    __builtin_amdgcn_s_setprio(1); \
    _Pragma("unroll") for (int mf_ = 0; mf_ < 4; ++mf_) \
    _Pragma("unroll") for (int nf_ = 0; nf_ < 4; ++nf_) \
      acc[(OFS) + mf_][nf_] = __builtin_amdgcn_mfma_f32_16x16x32_bf16( \
          AF[mf_], BF[nf_], acc[(OFS) + mf_][nf_], 0, 0, 0); \
    __builtin_amdgcn_s_setprio(0); \
  } while (0)

#define TILE(T, CUR, DO_B1, DO_T2, VMN) do { \
    short8 a0[4], a1[4], a2[4], a3[4], b0[4], b1[4]; \
    _Pragma("unroll") for (int i = 0; i < 4; ++i) \
      a0[i] = *(const short8*)&As[CUR][wm][(i * 16 + fr) * 64 + s0]; \
    _Pragma("unroll") for (int i = 0; i < 4; ++i) \
      b0[i] = *(const short8*)&Bs[CUR][hB][(rB0 + i * 16 + fr) * 64 + s0]; \
    if (DO_B1) STG_B(1, (T) + 1, (CUR) ^ 1); \
    BARR; LGKM0; MF16(a0, b0, 0); BARR; \
    _Pragma("unroll") for (int i = 0; i < 4; ++i) \
      a1[i] = *(const short8*)&As[CUR][wm][((i + 4) * 16 + fr) * 64 + s0]; \
    _Pragma("unroll") for (int i = 0; i < 4; ++i) \
      b1[i] = *(const short8*)&Bs[CUR][hB][(rB0 + i * 16 + fr) * 64 + s1]; \
    BARR; LGKM0; MF16(a1, b0, 4); BARR; \
    _Pragma("unroll") for (int i = 0; i < 4; ++i) \
      a2[i] = *(const short8*)&As[CUR][wm][(i * 16 + fr) * 64 + s1]; \
    _Pragma("unroll") for (int i = 0; i < 4; ++i) \
      a3[i] = *(const short8*)&As[CUR][wm][((i + 4) * 16 + fr) * 64 + s1]; \
    if (DO_T2) STG_B(0, (T) + 2, (CUR)); \
    BARR; LGKM0; MF16(a2, b1, 0); BARR; \
    if (DO_T2) { STG_A(0, (T) + 2, (CUR)); STG_A(1, (T) + 2, (CUR)); } \
    if ((VMN) == 6) asm volatile("s_waitcnt vmcnt(6)" ::: "memory"); \
    else if ((VMN) == 0) asm volatile("s_waitcnt vmcnt(0)" ::: "memory"); \
    BARR; MF16(a3, b1, 4); BARR; \
  } while (0)

  asm volatile("s_waitcnt vmcnt(0)" ::: "memory");
  STG_A(0, 0, 0); STG_A(1, 0, 0); STG_B(0, 0, 0); STG_B(1, 0, 0);
  STG_B(0, 1, 1); STG_A(0, 1, 1); STG_A(1, 1, 1);
  asm volatile("s_waitcnt vmcnt(6)" ::: "memory");
  BARR;

  for (int t = 0; t < 6; t += 2) { TILE(t, 0, 1, 1, 6); TILE(t + 1, 1, 1, 1, 6); }
  TILE(6, 0, 1, 0, 0);
  TILE(7, 1, 0, 0, -1);

#undef TILE
#undef STG_A
#undef STG_B

  // ======== epilogue via LDS roundtrip (LDS dead after final barrier) ========
  // D frag: col = fr, row = fk*4 + r.
  if (m0 == 512) {
    // thT: LDS [local col 0..127][264] ; 2 passes over col halves
#pragma unroll
    for (int p = 0; p < 2; ++p) {
      if ((wn >> 1) == p) {
        const int lcb = (wn & 1) * 64;
#pragma unroll
        for (int m = 0; m < 8; ++m) {
          int jr = wm * 128 + m * 16 + fk * 4;
#pragma unroll
          for (int n = 0; n < 4; ++n) {
            int lc = lcb + n * 16 + fr;
            us4 o;
#pragma unroll
            for (int r = 0; r < 4; ++r) o[r] = f2b(acc[m][n][r] + bias[512 + jr + r]);
            *reinterpret_cast<us4*>(&SM[lc * 264 + jr]) = o;
          }
        }
      }
      BARR;
#pragma unroll
      for (int it = 0; it < 8; ++it) {
        int idx = it * 512 + tid;
        int lc = idx >> 5, ch = idx & 31;
        int col = n0 + p * 128 + lc;
        if (col < NSP)
          *reinterpret_cast<us8*>(&thT[((size_t)b * NSP + col) * 256 + ch * 8]) =
              *reinterpret_cast<const us8*>(&SM[lc * 264 + ch * 8]);
      }
      BARR;
    }
  } else {
    // P (g/ph): LDS [local row 0..127][264] ; 2 passes over row halves
    us8 z = {0, 0, 0, 0, 0, 0, 0, 0};
#pragma unroll
    for (int p = 0; p < 2; ++p) {
      if (wm == p) {
#pragma unroll
        for (int m = 0; m < 8; ++m) {
#pragma unroll
          for (int n = 0; n < 4; ++n) {
            int col = wn * 64 + n * 16 + fr;
#pragma unroll
            for (int r = 0; r < 4; ++r) {
              int lrow = m * 16 + fk * 4 + r;
              SM[lrow * 264 + col] = f2b(acc[m][n][r] + bias[m0 + p * 128 + lrow]);
            }
          }
        }
      }
      BARR;
#pragma unroll
      for (int it = 0; it < 8; ++it) {
        int idx = it * 512 + tid;
        int row = idx >> 5, ch = idx & 31;
        int gcol = n0 + ch * 8;
        if (gcol < PLD) {
          us8 v = (gcol < NSP) ? *reinterpret_cast<const us8*>(&SM[row * 264 + ch * 8]) : z;
          *reinterpret_cast<us8*>(
              &P[(size_t)b * 512 * PLD + (size_t)(m0 + p * 128 + row) * PLD + gcol]) = v;
        }
      }
      BARR;
    }
  }
}

// ==================== small GEMMs (128^2, BK=64, swizzled) ====================
// MODE 2: Mf2 = ph .NT g    (M=256, N=256, K=3200 split 5x640) f32
// MODE 6: U   = Ww .NT MT2  (M=512, N=256, K=256) bf16
// MODE 4: out = U  .NT thT + x + W_b (M=512, N=3328 tiles, K=256) f32
template<int MODE>
__global__ __launch_bounds__(256, 2) void gemm64(
    const ushort_t* __restrict__ Abase,
    const ushort_t* __restrict__ Bbase,
    void* __restrict__ Cbase,
    const float* __restrict__ bias,
    const float* __restrict__ xres)
{
  constexpr int TB = 256;
  constexpr int MR = 4;
  constexpr int WN = 2;
  constexpr int CH = TB / 8;

  const int nwg = gridDim.x * gridDim.y * gridDim.z;
  int flat = blockIdx.x + gridDim.x * (blockIdx.y + gridDim.y * blockIdx.z);
  const int q = nwg >> 3;
  int swz = (flat & 7) * q + (flat >> 3);
  const int bx = swz % gridDim.x; int tmp = swz / gridDim.x;
  const int by = tmp % gridDim.y;
  const int bz = tmp / gridDim.y;

  int b, kc = 0, kbeg, kend, lda, ldb;
  const ushort_t *A, *B;
  if constexpr (MODE == 2) {
    b = bz & 15; kc = bz >> 4;
    A = Abase + (size_t)b * 512 * PLD + (size_t)256 * PLD;  // ph
    B = Abase + (size_t)b * 512 * PLD;                      // g
    lda = PLD; ldb = PLD; kbeg = kc * 640; kend = kbeg + 640;
  } else if constexpr (MODE == 6) {
    b = bz; A = Abase; lda = 256;
    B = Bbase + (size_t)b * 65536; ldb = 256;
    kbeg = 0; kend = 256;
  } else {
    b = bz; A = Abase + (size_t)b * 131072; lda = 256;
    B = Bbase + (size_t)b * NSP * 256; ldb = 256;
    kbeg = 0; kend = 256;
  }

  const int m0 = bx * 128;
  const int n0 = by * 128;
  const int tid = threadIdx.x;
  const int lane = tid & 63;
  const int wid = tid >> 6;
  const int wm = wid / WN, wn = wid % WN;
  const int fr = lane & 15;
  const int fk = lane >> 4;

  __shared__ __align__(16) ushort_t As[2][128 * 64];
  __shared__ __align__(16) ushort_t Bs[2][128 * 64];

  f32x4 acc[MR][4];
#pragma unroll
  for (int i = 0; i < MR; ++i)
#pragma unroll
    for (int j = 0; j < 4; ++j) acc[i][j] = f32x4{0.f, 0.f, 0.f, 0.f};

  const int srow = tid >> 3;
  const int lsl = (tid & 7) ^ (srow & 7);
  const ushort_t* pa = A + (size_t)(m0 + srow) * lda + kbeg + lsl * 8;
  const ushort_t* pb = B + (size_t)(n0 + srow) * ldb + kbeg + lsl * 8;

#define STAGE(bufi) do {                                                              \
    __builtin_amdgcn_global_load_lds(AS1(pa),                    AS3(&As[bufi][tid * 8]), 16, 0, 0); \
    __builtin_amdgcn_global_load_lds(AS1(pa + (size_t)CH * lda), AS3(&As[bufi][TB * 8 + tid * 8]), 16, 0, 0); \
    __builtin_amdgcn_global_load_lds(AS1(pa + (size_t)2 * CH * lda), AS3(&As[bufi][2 * TB * 8 + tid * 8]), 16, 0, 0); \
    __builtin_amdgcn_global_load_lds(AS1(pa + (size_t)3 * CH * lda), AS3(&As[bufi][3 * TB * 8 + tid * 8]), 16, 0, 0); \
    __builtin_amdgcn_global_load_lds(AS1(pb),                    AS3(&Bs[bufi][tid * 8]), 16, 0, 0); \
    __builtin_amdgcn_global_load_lds(AS1(pb + (size_t)CH * ldb), AS3(&Bs[bufi][TB * 8 + tid * 8]), 16, 0, 0); \
    __builtin_amdgcn_global_load_lds(AS1(pb + (size_t)2 * CH * ldb), AS3(&Bs[bufi][2 * TB * 8 + tid * 8]), 16, 0, 0); \
    __builtin_amdgcn_global_load_lds(AS1(pb + (size_t)3 * CH * ldb), AS3(&Bs[bufi][3 * TB * 8 + tid * 8]), 16, 0, 0); \
    pa += 64; pb += 64;                                                               \
  } while (0)

  const int sw = fr & 7;
  const int s0 = ((0 | fk) ^ sw) * 8;
  const int s1 = ((4 | fk) ^ sw) * 8;
  const int arow = (wm * MR * 16 + fr) * 64;
  const int brow = (wn * 64 + fr) * 64;

  asm volatile("s_waitcnt vmcnt(0)" ::: "memory");
  STAGE(0);

  const int nkt = (kend - kbeg) >> 6;
  for (int t = 0; t < nkt; ++t) {
    const int cur = t & 1;
    if (t + 1 < nkt) {
      STAGE(cur ^ 1);
      asm volatile("s_waitcnt vmcnt(8)" ::: "memory");
    } else {
      asm volatile("s_waitcnt vmcnt(0)" ::: "memory");
    }
    __builtin_amdgcn_s_barrier();
    __builtin_amdgcn_sched_barrier(0);

    short8 bf[4][2];
#pragma unroll
    for (int n = 0; n < 4; ++n) {
      bf[n][0] = *reinterpret_cast<const short8*>(&Bs[cur][brow + n * 1024 + s0]);
      bf[n][1] = *reinterpret_cast<const short8*>(&Bs[cur][brow + n * 1024 + s1]);
    }
    short8 af[4][2];
#pragma unroll
    for (int m = 0; m < 4; ++m) {
      af[m][0] = *reinterpret_cast<const short8*>(&As[cur][arow + m * 1024 + s0]);
      af[m][1] = *reinterpret_cast<const short8*>(&As[cur][arow + m * 1024 + s1]);
    }
    __builtin_amdgcn_s_setprio(1);
#pragma unroll
    for (int m = 0; m < 4; ++m)
#pragma unroll
      for (int n = 0; n < 4; ++n) {
        acc[m][n] = __builtin_amdgcn_mfma_f32_16x16x32_bf16(af[m][0], bf[n][0], acc[m][n], 0, 0, 0);
        acc[m][n] = __builtin_amdgcn_mfma_f32_16x16x32_bf16(af[m][1], bf[n][1], acc[m][n], 0, 0, 0);
      }
    __builtin_amdgcn_s_setprio(0);
    __builtin_amdgcn_s_barrier();
  }
#undef STAGE

  if constexpr (MODE == 2) {
    float* Mf = (float*)Cbase;
#pragma unroll
    for (int m = 0; m < MR; ++m)
#pragma unroll
      for (int n = 0; n < 4; ++n) {
        int gcol = n0 + wn * 64 + n * 16 + fr;
#pragma unroll
        for (int r = 0; r < 4; ++r) {
          int grow = m0 + wm * 64 + m * 16 + fk * 4 + r;
          Mf[((size_t)kc * 16 + b) * 65536 + grow * 256 + gcol] = acc[m][n][r];
        }
      }
  } else if constexpr (MODE == 6) {
    ushort_t* U = (ushort_t*)Cbase;
#pragma unroll
    for (int m = 0; m < MR; ++m)
#pragma unroll
      for (int n = 0; n < 4; ++n) {
        int gcol = n0 + wn * 64 + n * 16 + fr;
#pragma unroll
        for (int r = 0; r < 4; ++r) {
          int grow = m0 + wm * 64 + m * 16 + fk * 4 + r;
          U[(size_t)b * 131072 + grow * 256 + gcol] = f2b(acc[m][n][r]);
        }
      }
  } else {
    float* out = (float*)Cbase;
#pragma unroll
    for (int m = 0; m < MR; ++m)
#pragma unroll
      for (int n = 0; n < 4; ++n) {
        int gcol = n0 + wn * 64 + n * 16 + fr;
        if (gcol < NSP) {
#pragma unroll
          for (int r = 0; r < 4; ++r) {
            int grow = m0 + wm * 64 + m * 16 + fk * 4 + r;
            size_t o = ((size_t)b * 512 + grow) * NSP + gcol;
            out[o] = acc[m][n][r] + bias[grow] + xres[o];
          }
        }
      }
  }
}

// x [b][512][3136] f32 -> xb [b][3200][512] bf16
__global__ __launch_bounds__(256) void transp_x(const float* __restrict__ x,
                                                ushort_t* __restrict__ xb)
{
  const int nt = blockIdx.x, ct = blockIdx.y, b = blockIdx.z;
  const int t = threadIdx.x;
  const int n0 = nt * 64, c0 = ct * 64;
  __shared__ float Ls[64 * 65];

  const float* xs = x + (size_t)b * 512 * NSP;
#pragma unroll
  for (int p = 0; p < 4; ++p) {
    int cl = p * 16 + (t >> 4);
    int nl = (t & 15) * 4;
    f32x4 v = *reinterpret_cast<const f32x4*>(&xs[(size_t)(c0 + cl) * NSP + n0 + nl]);
    Ls[cl * 65 + nl + 0] = v[0];
    Ls[cl * 65 + nl + 1] = v[1];
    Ls[cl * 65 + nl + 2] = v[2];
    Ls[cl * 65 + nl + 3] = v[3];
  }
  __syncthreads();
#pragma unroll
  for (int it = 0; it < 2; ++it) {
    int idx = it * 256 + t; int nl = idx >> 3, cc = idx & 7;
    us8 o;
#pragma unroll
    for (int j = 0; j < 8; ++j) o[j] = f2b(Ls[(cc * 8 + j) * 65 + nl]);
    *reinterpret_cast<us8*>(&xb[((size_t)b * XNR + n0 + nl) * 512 + c0 + cc * 8]) = o;
  }
}

__global__ __launch_bounds__(256) void prep_weights(
    const float* __restrict__ g_w, const float* __restrict__ ph_w,
    const float* __restrict__ th_w, const float* __restrict__ W_w,
    const float* __restrict__ g_b, const float* __restrict__ ph_b,
    const float* __restrict__ th_b,
    ushort_t* __restrict__ W3, ushort_t* __restrict__ Wwb,
    float* __restrict__ bias3)
{
  int i = blockIdx.x * 256 + threadIdx.x;
  if (i < 393216) {
    int row = i >> 9, col = i & 511;
    float v = (row < 256) ? g_w[row * 512 + col]
            : (row < 512) ? ph_w[(row - 256) * 512 + col]
                          : th_w[(row - 512) * 512 + col];
    W3[i] = f2b(v);
  } else if (i < 524288) {
    Wwb[i - 393216] = f2b(W_w[i - 393216]);
  } else if (i < 525056) {
    int r = i - 524288;
    bias3[r] = (r < 256) ? g_b[r] : (r < 512) ? ph_b[r - 256] : th_b[r - 512];
  }
}

__global__ __launch_bounds__(256) void cvt_M(const float* __restrict__ Mf,
                                             ushort_t* __restrict__ MT)
{
  int i = blockIdx.x * 256 + threadIdx.x;   // 16*256*256
  const int SL = 1048576;
  float s = 0.f;
#pragma unroll
  for (int k = 0; k < 5; ++k) s += Mf[(size_t)k * SL + i];
  MT[i] = f2b(s * (1.0f / 3136.0f));
}

extern "C" void kernel_launch(void* const* d_in, const int* in_sizes, int n_in,
                              void* d_out, int out_size, void* d_ws, size_t ws_size,
                              hipStream_t stream) {
  const float* x    = (const float*)d_in[0];
  const float* g_w  = (const float*)d_in[1];
  const float* g_b  = (const float*)d_in[2];
  const float* th_w = (const float*)d_in[3];
  const float* th_b = (const float*)d_in[4];
  const float* ph_w = (const float*)d_in[5];
  const float* ph_b = (const float*)d_in[6];
  const float* W_w  = (const float*)d_in[7];
  const float* W_b  = (const float*)d_in[8];

  char* ws = (char*)d_ws;
  ushort_t* xb   = (ushort_t*)(ws + 0);
  float*    Mf2  = (float*)(ws + 0);              // aliases xb (dead after G1)
  ushort_t* MT2  = (ushort_t*)(ws + 41943040);
  ushort_t* U    = (ushort_t*)(ws + 44040192);
  ushort_t* thT  = (ushort_t*)(ws + 52428800);
  ushort_t* P    = (ushort_t*)(ws + 78118912);
  ushort_t* W3   = (ushort_t*)(ws + 130547712);
  ushort_t* Wwb  = (ushort_t*)(ws + 131334144);
  float*    bias3 = (float*)(ws + 131596288);

  prep_weights<<<2052, 256, 0, stream>>>(g_w, ph_w, th_w, W_w, g_b, ph_b, th_b,
                                         W3, Wwb, bias3);
  transp_x<<<dim3(49, 8, 16), 256, 0, stream>>>(x, xb);

  // G1: P(g,ph) + thT = W3 .NT xb (+bias3)   M=768, N=3328-tiled, K=512
  g1_8phase<<<dim3(3, 13, 16), 512, 0, stream>>>(W3, xb, P, thT, bias3);
  // G2: Mf2 partials = ph .NT g   split-K 5x640
  gemm64<2><<<dim3(2, 2, 80), 256, 0, stream>>>(P, nullptr, Mf2, nullptr, nullptr);
  cvt_M<<<4096, 256, 0, stream>>>(Mf2, MT2);
  // GU: U = Wwb .NT MT2            M=512, N=256, K=256
  gemm64<6><<<dim3(4, 2, 16), 256, 0, stream>>>(Wwb, MT2, U, nullptr, nullptr);
  // G4: out = U .NT thT + x + W_b  M=512, N=3328-tiled, K=256
  gemm64<4><<<dim3(4, 26, 16), 256, 0, stream>>>(U, thT, d_out, W_b, x);
}

// Round 7
// 170.386 us; speedup vs baseline: 1.3825x; 1.1045x over previous
//
#include <hip/hip_runtime.h>
#include <stdint.h>

// ---------------------------------------------------------------------------
// NonLocalBlock2D  B=16, C=512, I=256, N=3136.
//   xb  [b][3200][512] = x^T bf16
//   G1 (256^2, 8-phase): rows<512 -> P[b][512][3200] (g,ph)
//                        rows>=512 -> thT[b][3136][256] (transposed store)
//   Epilogues go through LDS staging -> coalesced wide stores.
//   G2 (128^2): Mf2 partials = ph .NT g, split-K 5x640
//   cvt: MT2 = (1/N) sum partials
//   GU (128^2): U = Ww .NT MT2
//   G4 (128^2): out = U .NT thT + x + W_b   (LDS-roundtrip f32 epilogue)
// ---------------------------------------------------------------------------

typedef unsigned short ushort_t;
typedef __attribute__((ext_vector_type(8))) short short8;
typedef __attribute__((ext_vector_type(4))) float f32x4;
typedef __attribute__((ext_vector_type(4))) unsigned short us4;
typedef __attribute__((ext_vector_type(8))) unsigned short us8;

#define NSP  3136
#define XNR  3200
#define PLD  3200

#define AS1(p) ((const __attribute__((address_space(1))) void*)(p))
#define AS3(p) ((__attribute__((address_space(3))) void*)(p))

__device__ inline ushort_t f2b(float f) {
  union { float f; uint32_t u; } c; c.f = f;
  uint32_t u = c.u;
  uint32_t r = (u + 0x7fffu + ((u >> 16) & 1u)) >> 16;
  return (ushort_t)r;
}

// ============================ G1: 8-phase 256^2 ============================
__global__ __launch_bounds__(512, 2) void g1_8phase(
    const ushort_t* __restrict__ W3,
    const ushort_t* __restrict__ xbase,
    ushort_t* __restrict__ P,
    ushort_t* __restrict__ thT,
    const float* __restrict__ bias)
{
  const int nwg = gridDim.x * gridDim.y * gridDim.z;   // 624, %8==0
  int flat = blockIdx.x + gridDim.x * (blockIdx.y + gridDim.y * blockIdx.z);
  const int q = nwg >> 3;
  int swz = (flat & 7) * q + (flat >> 3);
  const int bx = swz % gridDim.x; int tmp = swz / gridDim.x;
  const int by = tmp % gridDim.y;
  const int b  = tmp / gridDim.y;

  const int m0 = bx * 256;
  const int n0 = by * 256;
  const ushort_t* Ag = W3;
  const ushort_t* Bg = xbase + (size_t)b * XNR * 512;

  const int tid = threadIdx.x;
  const int lane = tid & 63;
  const int wid = tid >> 6;
  const int wm = wid >> 2;            // 0..1  (m-half)
  const int wn = wid & 3;             // 0..3
  const int fr = lane & 15;
  const int fk = lane >> 4;           // 0..3
  const int hB = wn >> 1;             // B half
  const int rB0 = (wn & 1) * 64;
  const int s0 = ((fk) ^ (fr & 7)) * 8;        // k-half0 swizzled slot
  const int s1 = ((4 | fk) ^ (fr & 7)) * 8;    // k-half1
  const int rth = tid >> 3;                    // 0..63
  const int swc = ((tid & 7) ^ ((tid >> 3) & 7)) * 8;  // pre-swizzled src col

  __shared__ __align__(16) ushort_t SM[65536];          // 128 KiB, re-used by epilogue
  ushort_t (*As)[2][8192] = (ushort_t(*)[2][8192])(SM);
  ushort_t (*Bs)[2][8192] = (ushort_t(*)[2][8192])(SM + 32768);

  f32x4 acc[8][4];
#pragma unroll
  for (int i = 0; i < 8; ++i)
#pragma unroll
    for (int j = 0; j < 4; ++j) acc[i][j] = f32x4{0.f, 0.f, 0.f, 0.f};

#define STG_A(h, kt, BUF) do { \
    const ushort_t* s_ = Ag + (size_t)(m0 + (h) * 128 + rth) * 512 + (kt) * 64 + swc; \
    __builtin_amdgcn_global_load_lds(AS1(s_), AS3(&As[BUF][h][tid * 8]), 16, 0, 0); \
    __builtin_amdgcn_global_load_lds(AS1(s_ + 64 * 512), AS3(&As[BUF][h][4096 + tid * 8]), 16, 0, 0); \
  } while (0)
#define STG_B(h, kt, BUF) do { \
    const ushort_t* s_ = Bg + (size_t)(n0 + (h) * 128 + rth) * 512 + (kt) * 64 + swc; \
    __builtin_amdgcn_global_load_lds(AS1(s_), AS3(&Bs[BUF][h][tid * 8]), 16, 0, 0); \
    __builtin_amdgcn_global_load_lds(AS1(s_ + 64 * 512), AS3(&Bs[BUF][h][4096 + tid * 8]), 16, 0, 0); \
  } while (0)

#define BARR __builtin_amdgcn_s_barrier()
#define LGKM0 do { asm volatile("s_waitcnt lgkmcnt(0)" ::: "memory"); \
                   __builtin_amdgcn_sched_barrier(0); } while (0)
#define MF16(AF, BF, OFS) do { \
    __builtin_amdgcn_s_setprio(1); \
    _Pragma("unroll") for (int mf_ = 0; mf_ < 4; ++mf_) \
    _Pragma("unroll") for (int nf_ = 0; nf_ < 4; ++nf_) \
      acc[(OFS) + mf_][nf_] = __builtin_amdgcn_mfma_f32_16x16x32_bf16( \
          AF[mf_], BF[nf_], acc[(OFS) + mf_][nf_], 0, 0, 0); \
    __builtin_amdgcn_s_setprio(0); \
  } while (0)

#define TILE(T, CUR, DO_B1, DO_T2, VMN) do { \
    short8 a0[4], a1[4], a2[4], a3[4], b0[4], b1[4]; \
    _Pragma("unroll") for (int i = 0; i < 4; ++i) \
      a0[i] = *(const short8*)&As[CUR][wm][(i * 16 + fr) * 64 + s0]; \
    _Pragma("unroll") for (int i = 0; i < 4; ++i) \
      b0[i] = *(const short8*)&Bs[CUR][hB][(rB0 + i * 16 + fr) * 64 + s0]; \
    if (DO_B1) STG_B(1, (T) + 1, (CUR) ^ 1); \
    BARR; LGKM0; MF16(a0, b0, 0); BARR; \
    _Pragma("unroll") for (int i = 0; i < 4; ++i) \
      a1[i] = *(const short8*)&As[CUR][wm][((i + 4) * 16 + fr) * 64 + s0]; \
    _Pragma("unroll") for (int i = 0; i < 4; ++i) \
      b1[i] = *(const short8*)&Bs[CUR][hB][(rB0 + i * 16 + fr) * 64 + s1]; \
    BARR; LGKM0; MF16(a1, b0, 4); BARR; \
    _Pragma("unroll") for (int i = 0; i < 4; ++i) \
      a2[i] = *(const short8*)&As[CUR][wm][(i * 16 + fr) * 64 + s1]; \
    _Pragma("unroll") for (int i = 0; i < 4; ++i) \
      a3[i] = *(const short8*)&As[CUR][wm][((i + 4) * 16 + fr) * 64 + s1]; \
    if (DO_T2) STG_B(0, (T) + 2, (CUR)); \
    BARR; LGKM0; MF16(a2, b1, 0); BARR; \
    if (DO_T2) { STG_A(0, (T) + 2, (CUR)); STG_A(1, (T) + 2, (CUR)); } \
    if ((VMN) == 6) asm volatile("s_waitcnt vmcnt(6)" ::: "memory"); \
    else if ((VMN) == 0) asm volatile("s_waitcnt vmcnt(0)" ::: "memory"); \
    BARR; MF16(a3, b1, 4); BARR; \
  } while (0)

  asm volatile("s_waitcnt vmcnt(0)" ::: "memory");
  STG_A(0, 0, 0); STG_A(1, 0, 0); STG_B(0, 0, 0); STG_B(1, 0, 0);
  STG_B(0, 1, 1); STG_A(0, 1, 1); STG_A(1, 1, 1);
  asm volatile("s_waitcnt vmcnt(6)" ::: "memory");
  BARR;

  for (int t = 0; t < 6; t += 2) { TILE(t, 0, 1, 1, 6); TILE(t + 1, 1, 1, 1, 6); }
  TILE(6, 0, 1, 0, 0);
  TILE(7, 1, 0, 0, -1);

#undef TILE
#undef STG_A
#undef STG_B

  // ======== epilogue via LDS roundtrip (LDS dead after final barrier) ========
  // D frag: col = fr, row = fk*4 + r.
  if (m0 == 512) {
    // thT: LDS [local col 0..127][264] ; 2 passes over col halves
#pragma unroll
    for (int p = 0; p < 2; ++p) {
      if ((wn >> 1) == p) {
        const int lcb = (wn & 1) * 64;
#pragma unroll
        for (int m = 0; m < 8; ++m) {
          int jr = wm * 128 + m * 16 + fk * 4;
#pragma unroll
          for (int n = 0; n < 4; ++n) {
            int lc = lcb + n * 16 + fr;
            us4 o;
#pragma unroll
            for (int r = 0; r < 4; ++r) o[r] = f2b(acc[m][n][r] + bias[512 + jr + r]);
            *reinterpret_cast<us4*>(&SM[lc * 264 + jr]) = o;
          }
        }
      }
      BARR;
#pragma unroll
      for (int it = 0; it < 8; ++it) {
        int idx = it * 512 + tid;
        int lc = idx >> 5, ch = idx & 31;
        int col = n0 + p * 128 + lc;
        if (col < NSP)
          *reinterpret_cast<us8*>(&thT[((size_t)b * NSP + col) * 256 + ch * 8]) =
              *reinterpret_cast<const us8*>(&SM[lc * 264 + ch * 8]);
      }
      BARR;
    }
  } else {
    // P (g/ph): LDS [local row 0..127][264] ; 2 passes over row halves
    us8 z = {0, 0, 0, 0, 0, 0, 0, 0};
#pragma unroll
    for (int p = 0; p < 2; ++p) {
      if (wm == p) {
#pragma unroll
        for (int m = 0; m < 8; ++m) {
#pragma unroll
          for (int n = 0; n < 4; ++n) {
            int col = wn * 64 + n * 16 + fr;
#pragma unroll
            for (int r = 0; r < 4; ++r) {
              int lrow = m * 16 + fk * 4 + r;
              SM[lrow * 264 + col] = f2b(acc[m][n][r] + bias[m0 + p * 128 + lrow]);
            }
          }
        }
      }
      BARR;
#pragma unroll
      for (int it = 0; it < 8; ++it) {
        int idx = it * 512 + tid;
        int row = idx >> 5, ch = idx & 31;
        int gcol = n0 + ch * 8;
        if (gcol < PLD) {
          us8 v = (gcol < NSP) ? *reinterpret_cast<const us8*>(&SM[row * 264 + ch * 8]) : z;
          *reinterpret_cast<us8*>(
              &P[(size_t)b * 512 * PLD + (size_t)(m0 + p * 128 + row) * PLD + gcol]) = v;
        }
      }
      BARR;
    }
  }
}

// ==================== small GEMMs (128^2, BK=64, swizzled) ====================
// MODE 2: Mf2 = ph .NT g    (M=256, N=256, K=3200 split 5x640) f32
// MODE 6: U   = Ww .NT MT2  (M=512, N=256, K=256) bf16
// MODE 4: out = U  .NT thT + x + W_b (M=512, N=3328 tiles, K=256) f32
template<int MODE>
__global__ __launch_bounds__(256, 2) void gemm64(
    const ushort_t* __restrict__ Abase,
    const ushort_t* __restrict__ Bbase,
    void* __restrict__ Cbase,
    const float* __restrict__ bias,
    const float* __restrict__ xres)
{
  constexpr int TB = 256;
  constexpr int MR = 4;
  constexpr int WN = 2;
  constexpr int CH = TB / 8;

  const int nwg = gridDim.x * gridDim.y * gridDim.z;
  int flat = blockIdx.x + gridDim.x * (blockIdx.y + gridDim.y * blockIdx.z);
  const int q = nwg >> 3;
  int swz = (flat & 7) * q + (flat >> 3);
  const int bx = swz % gridDim.x; int tmp = swz / gridDim.x;
  const int by = tmp % gridDim.y;
  const int bz = tmp / gridDim.y;

  int b, kc = 0, kbeg, kend, lda, ldb;
  const ushort_t *A, *B;
  if constexpr (MODE == 2) {
    b = bz & 15; kc = bz >> 4;
    A = Abase + (size_t)b * 512 * PLD + (size_t)256 * PLD;  // ph
    B = Abase + (size_t)b * 512 * PLD;                      // g
    lda = PLD; ldb = PLD; kbeg = kc * 640; kend = kbeg + 640;
  } else if constexpr (MODE == 6) {
    b = bz; A = Abase; lda = 256;
    B = Bbase + (size_t)b * 65536; ldb = 256;
    kbeg = 0; kend = 256;
  } else {
    b = bz; A = Abase + (size_t)b * 131072; lda = 256;
    B = Bbase + (size_t)b * NSP * 256; ldb = 256;
    kbeg = 0; kend = 256;
  }

  const int m0 = bx * 128;
  const int n0 = by * 128;
  const int tid = threadIdx.x;
  const int lane = tid & 63;
  const int wid = tid >> 6;
  const int wm = wid / WN, wn = wid % WN;
  const int fr = lane & 15;
  const int fk = lane >> 4;

  __shared__ __align__(16) ushort_t SMu[32768];   // 64 KiB: As | Bs, reused by MODE4 epilogue
  ushort_t (*As)[8192] = (ushort_t(*)[8192])(SMu);
  ushort_t (*Bs)[8192] = (ushort_t(*)[8192])(SMu + 16384);

  f32x4 acc[MR][4];
#pragma unroll
  for (int i = 0; i < MR; ++i)
#pragma unroll
    for (int j = 0; j < 4; ++j) acc[i][j] = f32x4{0.f, 0.f, 0.f, 0.f};

  const int srow = tid >> 3;
  const int lsl = (tid & 7) ^ (srow & 7);
  const ushort_t* pa = A + (size_t)(m0 + srow) * lda + kbeg + lsl * 8;
  const ushort_t* pb = B + (size_t)(n0 + srow) * ldb + kbeg + lsl * 8;

#define STAGE(bufi) do {                                                              \
    __builtin_amdgcn_global_load_lds(AS1(pa),                    AS3(&As[bufi][tid * 8]), 16, 0, 0); \
    __builtin_amdgcn_global_load_lds(AS1(pa + (size_t)CH * lda), AS3(&As[bufi][TB * 8 + tid * 8]), 16, 0, 0); \
    __builtin_amdgcn_global_load_lds(AS1(pa + (size_t)2 * CH * lda), AS3(&As[bufi][2 * TB * 8 + tid * 8]), 16, 0, 0); \
    __builtin_amdgcn_global_load_lds(AS1(pa + (size_t)3 * CH * lda), AS3(&As[bufi][3 * TB * 8 + tid * 8]), 16, 0, 0); \
    __builtin_amdgcn_global_load_lds(AS1(pb),                    AS3(&Bs[bufi][tid * 8]), 16, 0, 0); \
    __builtin_amdgcn_global_load_lds(AS1(pb + (size_t)CH * ldb), AS3(&Bs[bufi][TB * 8 + tid * 8]), 16, 0, 0); \
    __builtin_amdgcn_global_load_lds(AS1(pb + (size_t)2 * CH * ldb), AS3(&Bs[bufi][2 * TB * 8 + tid * 8]), 16, 0, 0); \
    __builtin_amdgcn_global_load_lds(AS1(pb + (size_t)3 * CH * ldb), AS3(&Bs[bufi][3 * TB * 8 + tid * 8]), 16, 0, 0); \
    pa += 64; pb += 64;                                                               \
  } while (0)

  const int sw = fr & 7;
  const int s0 = ((0 | fk) ^ sw) * 8;
  const int s1 = ((4 | fk) ^ sw) * 8;
  const int arow = (wm * MR * 16 + fr) * 64;
  const int brow = (wn * 64 + fr) * 64;

  asm volatile("s_waitcnt vmcnt(0)" ::: "memory");
  STAGE(0);

  const int nkt = (kend - kbeg) >> 6;
  for (int t = 0; t < nkt; ++t) {
    const int cur = t & 1;
    if (t + 1 < nkt) {
      STAGE(cur ^ 1);
      asm volatile("s_waitcnt vmcnt(8)" ::: "memory");
    } else {
      asm volatile("s_waitcnt vmcnt(0)" ::: "memory");
    }
    __builtin_amdgcn_s_barrier();
    __builtin_amdgcn_sched_barrier(0);

    short8 bf[4][2];
#pragma unroll
    for (int n = 0; n < 4; ++n) {
      bf[n][0] = *reinterpret_cast<const short8*>(&Bs[cur][brow + n * 1024 + s0]);
      bf[n][1] = *reinterpret_cast<const short8*>(&Bs[cur][brow + n * 1024 + s1]);
    }
    short8 af[4][2];
#pragma unroll
    for (int m = 0; m < 4; ++m) {
      af[m][0] = *reinterpret_cast<const short8*>(&As[cur][arow + m * 1024 + s0]);
      af[m][1] = *reinterpret_cast<const short8*>(&As[cur][arow + m * 1024 + s1]);
    }
    __builtin_amdgcn_s_setprio(1);
#pragma unroll
    for (int m = 0; m < 4; ++m)
#pragma unroll
      for (int n = 0; n < 4; ++n) {
        acc[m][n] = __builtin_amdgcn_mfma_f32_16x16x32_bf16(af[m][0], bf[n][0], acc[m][n], 0, 0, 0);
        acc[m][n] = __builtin_amdgcn_mfma_f32_16x16x32_bf16(af[m][1], bf[n][1], acc[m][n], 0, 0, 0);
      }
    __builtin_amdgcn_s_setprio(0);
    __builtin_amdgcn_s_barrier();
  }
#undef STAGE

  if constexpr (MODE == 2) {
    float* Mf = (float*)Cbase;
#pragma unroll
    for (int m = 0; m < MR; ++m)
#pragma unroll
      for (int n = 0; n < 4; ++n) {
        int gcol = n0 + wn * 64 + n * 16 + fr;
#pragma unroll
        for (int r = 0; r < 4; ++r) {
          int grow = m0 + wm * 64 + m * 16 + fk * 4 + r;
          Mf[((size_t)kc * 16 + b) * 65536 + grow * 256 + gcol] = acc[m][n][r];
        }
      }
  } else if constexpr (MODE == 6) {
    ushort_t* U = (ushort_t*)Cbase;
#pragma unroll
    for (int m = 0; m < MR; ++m)
#pragma unroll
      for (int n = 0; n < 4; ++n) {
        int gcol = n0 + wn * 64 + n * 16 + fr;
#pragma unroll
        for (int r = 0; r < 4; ++r) {
          int grow = m0 + wm * 64 + m * 16 + fk * 4 + r;
          U[(size_t)b * 131072 + grow * 256 + gcol] = f2b(acc[m][n][r]);
        }
      }
  } else {
    // -------- MODE 4: LDS-roundtrip f32 epilogue, float4-coalesced --------
    float* out = (float*)Cbase;
    float* SMf = (float*)SMu;       // 64 rows x 132 floats = 33792 B of 64 KiB
#pragma unroll
    for (int p = 0; p < 2; ++p) {
      if (wm == p) {
#pragma unroll
        for (int m = 0; m < MR; ++m)
#pragma unroll
          for (int n = 0; n < 4; ++n) {
            int col = wn * 64 + n * 16 + fr;
#pragma unroll
            for (int r = 0; r < 4; ++r)
              SMf[(m * 16 + fk * 4 + r) * 132 + col] = acc[m][n][r];
          }
      }
      __builtin_amdgcn_s_barrier();
#pragma unroll
      for (int it = 0; it < 8; ++it) {
        int idx = it * 256 + tid;
        int row = idx >> 5, ch = idx & 31;
        int gcol = n0 + ch * 4;
        if (gcol < NSP) {
          int grow = m0 + p * 64 + row;
          size_t o = ((size_t)b * 512 + grow) * NSP + gcol;
          f32x4 v = *reinterpret_cast<const f32x4*>(&SMf[row * 132 + ch * 4]);
          f32x4 xr = *reinterpret_cast<const f32x4*>(&xres[o]);
          float bi = bias[grow];
          f32x4 ov = {v[0] + bi + xr[0], v[1] + bi + xr[1],
                      v[2] + bi + xr[2], v[3] + bi + xr[3]};
          *reinterpret_cast<f32x4*>(&out[o]) = ov;
        }
      }
      __builtin_amdgcn_s_barrier();
    }
  }
}

// x [b][512][3136] f32 -> xb [b][3200][512] bf16
__global__ __launch_bounds__(256) void transp_x(const float* __restrict__ x,
                                                ushort_t* __restrict__ xb)
{
  const int nt = blockIdx.x, ct = blockIdx.y, b = blockIdx.z;
  const int t = threadIdx.x;
  const int n0 = nt * 64, c0 = ct * 64;
  __shared__ float Ls[64 * 65];

  const float* xs = x + (size_t)b * 512 * NSP;
#pragma unroll
  for (int p = 0; p < 4; ++p) {
    int cl = p * 16 + (t >> 4);
    int nl = (t & 15) * 4;
    f32x4 v = *reinterpret_cast<const f32x4*>(&xs[(size_t)(c0 + cl) * NSP + n0 + nl]);
    Ls[cl * 65 + nl + 0] = v[0];
    Ls[cl * 65 + nl + 1] = v[1];
    Ls[cl * 65 + nl + 2] = v[2];
    Ls[cl * 65 + nl + 3] = v[3];
  }
  __syncthreads();
#pragma unroll
  for (int it = 0; it < 2; ++it) {
    int idx = it * 256 + t; int nl = idx >> 3, cc = idx & 7;
    us8 o;
#pragma unroll
    for (int j = 0; j < 8; ++j) o[j] = f2b(Ls[(cc * 8 + j) * 65 + nl]);
    *reinterpret_cast<us8*>(&xb[((size_t)b * XNR + n0 + nl) * 512 + c0 + cc * 8]) = o;
  }
}

__global__ __launch_bounds__(256) void prep_weights(
    const float* __restrict__ g_w, const float* __restrict__ ph_w,
    const float* __restrict__ th_w, const float* __restrict__ W_w,
    const float* __restrict__ g_b, const float* __restrict__ ph_b,
    const float* __restrict__ th_b,
    ushort_t* __restrict__ W3, ushort_t* __restrict__ Wwb,
    float* __restrict__ bias3)
{
  int i = blockIdx.x * 256 + threadIdx.x;
  if (i < 393216) {
    int row = i >> 9, col = i & 511;
    float v = (row < 256) ? g_w[row * 512 + col]
            : (row < 512) ? ph_w[(row - 256) * 512 + col]
                          : th_w[(row - 512) * 512 + col];
    W3[i] = f2b(v);
  } else if (i < 524288) {
    Wwb[i - 393216] = f2b(W_w[i - 393216]);
  } else if (i < 525056) {
    int r = i - 524288;
    bias3[r] = (r < 256) ? g_b[r] : (r < 512) ? ph_b[r - 256] : th_b[r - 512];
  }
}

__global__ __launch_bounds__(256) void cvt_M(const float* __restrict__ Mf,
                                             ushort_t* __restrict__ MT)
{
  int i = blockIdx.x * 256 + threadIdx.x;   // 16*256*256
  const int SL = 1048576;
  float s = 0.f;
#pragma unroll
  for (int k = 0; k < 5; ++k) s += Mf[(size_t)k * SL + i];
  MT[i] = f2b(s * (1.0f / 3136.0f));
}

extern "C" void kernel_launch(void* const* d_in, const int* in_sizes, int n_in,
                              void* d_out, int out_size, void* d_ws, size_t ws_size,
                              hipStream_t stream) {
  const float* x    = (const float*)d_in[0];
  const float* g_w  = (const float*)d_in[1];
  const float* g_b  = (const float*)d_in[2];
  const float* th_w = (const float*)d_in[3];
  const float* th_b = (const float*)d_in[4];
  const float* ph_w = (const float*)d_in[5];
  const float* ph_b = (const float*)d_in[6];
  const float* W_w  = (const float*)d_in[7];
  const float* W_b  = (const float*)d_in[8];

  char* ws = (char*)d_ws;
  ushort_t* xb   = (ushort_t*)(ws + 0);
  float*    Mf2  = (float*)(ws + 0);              // aliases xb (dead after G1)
  ushort_t* MT2  = (ushort_t*)(ws + 41943040);
  ushort_t* U    = (ushort_t*)(ws + 44040192);
  ushort_t* thT  = (ushort_t*)(ws + 52428800);
  ushort_t* P    = (ushort_t*)(ws + 78118912);
  ushort_t* W3   = (ushort_t*)(ws + 130547712);
  ushort_t* Wwb  = (ushort_t*)(ws + 131334144);
  float*    bias3 = (float*)(ws + 131596288);

  prep_weights<<<2052, 256, 0, stream>>>(g_w, ph_w, th_w, W_w, g_b, ph_b, th_b,
                                         W3, Wwb, bias3);
  transp_x<<<dim3(49, 8, 16), 256, 0, stream>>>(x, xb);

  // G1: P(g,ph) + thT = W3 .NT xb (+bias3)   M=768, N=3328-tiled, K=512
  g1_8phase<<<dim3(3, 13, 16), 512, 0, stream>>>(W3, xb, P, thT, bias3);
  // G2: Mf2 partials = ph .NT g   split-K 5x640
  gemm64<2><<<dim3(2, 2, 80), 256, 0, stream>>>(P, nullptr, Mf2, nullptr, nullptr);
  cvt_M<<<4096, 256, 0, stream>>>(Mf2, MT2);
  // GU: U = Wwb .NT MT2            M=512, N=256, K=256
  gemm64<6><<<dim3(4, 2, 16), 256, 0, stream>>>(Wwb, MT2, U, nullptr, nullptr);
  // G4: out = U .NT thT + x + W_b  M=512, N=3328-tiled, K=256
  gemm64<4><<<dim3(4, 26, 16), 256, 0, stream>>>(U, thT, d_out, W_b, x);
}